// Round 7
// baseline (172.629 us; speedup 1.0000x reference)
//
#include <hip/hip_runtime.h>
#include <hip/hip_bf16.h>
#include <hip/hip_fp16.h>
#include <cfloat>

#define N_NODES 50000
#define N_EDGES 800000
#define FEAT 128
#define BATCH 2
#define RTOT (BATCH*N_NODES)

typedef __bf16 bf16x8 __attribute__((ext_vector_type(8)));
typedef float  f32x4  __attribute__((ext_vector_type(4)));

__device__ inline unsigned short f2bf(float f){
  unsigned int u = __float_as_uint(f);
  u = (u + 0x7fffu + ((u >> 16) & 1u)) >> 16;
  return (unsigned short)u;
}

// ---- prep: W1t/W2t = bf16(W^T) pre-swizzled; zero cnt ----
__global__ void k_prep(const float* __restrict__ W1, const float* __restrict__ W2,
                       __bf16* __restrict__ W1t, __bf16* __restrict__ W2t,
                       int* __restrict__ cnt){
  int i = blockIdx.x*blockDim.x + threadIdx.x;
  if(i < FEAT*FEAT){
    int k = i >> 7, col = i & 127;
    int sw = (col << 7) + (k ^ ((col & 7) << 3));
    W1t[sw] = (__bf16)W1[i];
    W2t[sw] = (__bf16)W2[i];
  }
  if(i < N_NODES) cnt[i] = 0;
}

// ---- GEMM1 (MFMA, swapped operands): g[n][b][128]=bf16(h@W1), s_i/s_j[n][b]; fused hist ----
// mfma(Wfrag, hfrag): lane&15 = h-row, (lane>>4)*4+reg = g-col -> vectorized row stores.
__global__ __launch_bounds__(256) void k_gemm1_mfma(const float* __restrict__ h,
        const __bf16* __restrict__ W1t, const float* __restrict__ a,
        __bf16* __restrict__ g, float* __restrict__ s_i, float* __restrict__ s_j,
        const int* __restrict__ src, int* __restrict__ cnt)
{
  __shared__ __bf16 Bs[FEAT*FEAT];   // 32KB swizzled W^T
  int t = threadIdx.x, lane = t & 63, wid = t >> 6;
  {
    const float4* srcp = (const float4*)W1t;
    float4* dstp = (float4*)Bs;
    for(int i = t; i < FEAT*FEAT/8; i += 256) dstp[i] = srcp[i];
  }
  __syncthreads();

  int rb = blockIdx.x*64 + wid*16;
  int r  = rb + (lane & 15);
  int hgrp = lane >> 4;
  int kq = hgrp * 8;

  bf16x8 af[4];
  if(r < RTOT){
    const float* hrow = h + (size_t)r*FEAT + kq;
    #pragma unroll
    for(int ks = 0; ks < 4; ks++){
      float4 p0 = *(const float4*)(hrow + ks*32);
      float4 p1 = *(const float4*)(hrow + ks*32 + 4);
      bf16x8 v;
      v[0]=(__bf16)p0.x; v[1]=(__bf16)p0.y; v[2]=(__bf16)p0.z; v[3]=(__bf16)p0.w;
      v[4]=(__bf16)p1.x; v[5]=(__bf16)p1.y; v[6]=(__bf16)p1.z; v[7]=(__bf16)p1.w;
      af[ks] = v;
    }
  } else {
    #pragma unroll
    for(int ks = 0; ks < 4; ks++){ bf16x8 z = {}; af[ks] = z; }
  }

  f32x4 acc[8] = {};
  #pragma unroll
  for(int cb = 0; cb < 8; cb++){
    int col = cb*16 + (lane & 15);          // A'-row = g-col block
    int swbase = (col << 7);
    int swx = ((col & 7) << 3);
    #pragma unroll
    for(int ks = 0; ks < 4; ks++){
      int kb = ks*32 + kq;
      bf16x8 bf = *(const bf16x8*)&Bs[swbase + (kb ^ swx)];
      acc[cb] = __builtin_amdgcn_mfma_f32_16x16x32_bf16(bf, af[ks], acc[cb], 0, 0, 0);
    }
  }

  // epilogue: lane owns row r, cols {cb*16 + hgrp*4 + 0..3}
  if(r < RTOT){
    int b = (r >= N_NODES) ? 1 : 0;
    int n = r - b*N_NODES;
    __bf16* grow = g + (size_t)n*256 + b*128;
    float pi = 0.f, pj = 0.f;
    #pragma unroll
    for(int cb = 0; cb < 8; cb++){
      int c0 = cb*16 + hgrp*4;
      float4 al = *(const float4*)&a[c0];
      float4 ah = *(const float4*)&a[FEAT + c0];
      pi = fmaf(acc[cb][0], al.x, pi); pj = fmaf(acc[cb][0], ah.x, pj);
      pi = fmaf(acc[cb][1], al.y, pi); pj = fmaf(acc[cb][1], ah.y, pj);
      pi = fmaf(acc[cb][2], al.z, pi); pj = fmaf(acc[cb][2], ah.z, pj);
      pi = fmaf(acc[cb][3], al.w, pi); pj = fmaf(acc[cb][3], ah.w, pj);
      uint2 w;
      w.x = ((unsigned int)f2bf(acc[cb][1]) << 16) | f2bf(acc[cb][0]);
      w.y = ((unsigned int)f2bf(acc[cb][3]) << 16) | f2bf(acc[cb][2]);
      *(uint2*)(grow + c0) = w;
    }
    // reduce over the 4 hgrp copies of each row (lanes r, r+16, r+32, r+48)
    pi += __shfl_xor(pi, 16, 64); pj += __shfl_xor(pj, 16, 64);
    pi += __shfl_xor(pi, 32, 64); pj += __shfl_xor(pj, 32, 64);
    if(hgrp == 0){ s_i[n*2 + b] = pi; s_j[n*2 + b] = pj; }
  }

  // fused histogram over src (cnt pre-zeroed by k_prep)
  int gs = gridDim.x * 256;
  for(int e = blockIdx.x*256 + t; e < N_EDGES; e += gs)
    atomicAdd(&cnt[src[e]], 1);
}

// ---- single-kernel scan: block b sums its prefix directly, then local scan ----
__global__ __launch_bounds__(1024) void k_scan(const int* __restrict__ cnt,
                                               int* __restrict__ off, int* __restrict__ curs){
  __shared__ int s[1024];
  __shared__ int wsum[16];
  __shared__ int pfx;
  int t = threadIdx.x, b = blockIdx.x;
  // phase 1: prefix = sum cnt[0 .. b*1024)
  int ps = 0;
  int lim = b*1024;
  for(int i = t; i < lim; i += 1024) ps += cnt[i];
  #pragma unroll
  for(int mm=32; mm; mm>>=1) ps += __shfl_xor(ps, mm, 64);
  if((t & 63) == 0) wsum[t >> 6] = ps;
  __syncthreads();
  if(t == 0){
    int P = 0;
    #pragma unroll
    for(int w = 0; w < 16; w++) P += wsum[w];
    pfx = P;
  }
  // phase 2: local inclusive scan
  int idx = b*1024 + t;
  int v = (idx < N_NODES) ? cnt[idx] : 0;
  s[t] = v; __syncthreads();
  for(int st = 1; st < 1024; st <<= 1){
    int u = (t >= st) ? s[t-st] : 0;
    __syncthreads();
    s[t] += u;
    __syncthreads();
  }
  if(idx < N_NODES){
    int o = pfx + s[t] - v;
    off[idx] = o;
    curs[idx] = o;
  }
  if(b == 0 && t == 0) off[N_NODES] = N_EDGES;   // sentinel
}

// ---- fill: dst values in CSR-by-src order ----
__global__ void k_fill(const int* __restrict__ src, const int* __restrict__ dst,
                       int* __restrict__ curs, int* __restrict__ dste){
  int e = blockIdx.x*blockDim.x + threadIdx.x;
  if(e < N_EDGES){ int pos = atomicAdd(&curs[src[e]], 1); dste[pos] = dst[e]; }
}

// ---- FUSED aggregate + GEMM2 (swapped operands): block = 8 waves = 8 nodes ----
__global__ __launch_bounds__(512) void k_agg2(const unsigned int* __restrict__ g,
     const float* __restrict__ s_i, const float* __restrict__ s_j,
     const int* __restrict__ off,
     const int* __restrict__ dste, const __bf16* __restrict__ W2t,
     float* __restrict__ out)
{
  __shared__ __bf16 Bs[FEAT*FEAT];    // 32KB swizzled W2^T
  __shared__ __bf16 hpT[16*FEAT];     // 4KB swizzled A-tile (16 rows = 8 nodes x 2 batches)
  int t = threadIdx.x, lane = t & 63, w = t >> 6;
  {
    const float4* srcp = (const float4*)W2t;
    float4* dstp = (float4*)Bs;
    for(int i = t; i < FEAT*FEAT/8; i += 512) dstp[i] = srcp[i];
  }

  // ---- aggregation phase (one wave per node) ----
  int n = blockIdx.x*8 + w;           // N_NODES = 8*6250 exactly
  int o0 = off[n], deg = off[n+1] - o0;
  int half = lane >> 5, li = lane & 31;
  float si = s_i[n*2 + half];
  int selp = lane & 32;

  float denom = 0.f;
  float a0=0.f, a1=0.f, a2=0.f, a3=0.f;

  for(int base=0; base<deg; base+=32){
    int i = base + li;
    unsigned int wv = 0;                      // p=0, d=0 for inactive slots
    if(i < deg){
      int d = dste[o0 + i];                   // coalesced
      float xx = si + s_j[d*2 + half];        // scattered 4B gather (L2-resident)
      float x = (xx > 0.f) ? xx : 0.2f*xx;
      float p = __expf(x);                    // |x| small: no-max softmax is exact
      denom += p;
      wv = ((unsigned int)__half_as_ushort(__float2half(p)) << 16) | (unsigned int)d;
    }
    int lim = min(32, deg-base);
    int lim8 = (lim + 7) & ~7;
    for(int j=0; j<lim8; j+=8){
      unsigned int ww[8];
      #pragma unroll
      for(int c=0;c<8;c++) ww[c] = __shfl(wv, selp | (j+c), 64);
      uint2 u[8]; float q[8];
      #pragma unroll
      for(int c=0;c<8;c++){
        q[c] = __half2float(__ushort_as_half((unsigned short)(ww[c] >> 16)));
        u[c] = *(const uint2*)(g + (size_t)(ww[c] & 0xffffu)*128 + lane*2);
      }
      #pragma unroll
      for(int c=0;c<8;c++){
        a0 = fmaf(q[c], __uint_as_float(u[c].x << 16),         a0);
        a1 = fmaf(q[c], __uint_as_float(u[c].x & 0xffff0000u), a1);
        a2 = fmaf(q[c], __uint_as_float(u[c].y << 16),         a2);
        a3 = fmaf(q[c], __uint_as_float(u[c].y & 0xffff0000u), a3);
      }
    }
  }
  #pragma unroll
  for(int mm=16; mm; mm>>=1) denom += __shfl_xor(denom, mm, 64);  // per-half sum
  float inv = (denom > 0.f) ? 1.0f/denom : 0.f;

  // write hp row into swizzled LDS tile
  {
    int ri = w*2 + half;                 // tile row (node-major, batch-minor)
    int gidx = li >> 1;                  // 8-elem granule index of col 4*li
    int gsw = gidx ^ (ri & 7);
    int coff = gsw*8 + (li & 1)*4;
    unsigned int w0 = ((unsigned int)f2bf(a1*inv) << 16) | f2bf(a0*inv);
    unsigned int w1 = ((unsigned int)f2bf(a3*inv) << 16) | f2bf(a2*inv);
    uint2 o; o.x = w0; o.y = w1;
    *(uint2*)&hpT[ri*FEAT + coff] = o;
  }
  __syncthreads();

  // ---- GEMM2 phase (swapped): lane&15 = tile row, (lane>>4)*4+reg = col-in-block ----
  int r  = lane & 15;
  int kq16 = lane >> 4;                  // 0..3
  bf16x8 af[4];
  #pragma unroll
  for(int ks = 0; ks < 4; ks++){
    int gr = ks*4 + kq16;                // granule index along K
    int gsw2 = gr ^ (r & 7);
    af[ks] = *(const bf16x8*)&hpT[r*FEAT + gsw2*8];
  }
  f32x4 acc = {};
  int col = w*16 + (lane & 15);          // A'-row = out col
  int swbase = (col << 7);
  int swx = ((col & 7) << 3);
  #pragma unroll
  for(int ks = 0; ks < 4; ks++){
    int kb = ks*32 + kq16*8;
    bf16x8 bf = *(const bf16x8*)&Bs[swbase + (kb ^ swx)];
    acc = __builtin_amdgcn_mfma_f32_16x16x32_bf16(bf, af[ks], acc, 0, 0, 0);
  }
  // lane owns out row (node,b) = tile row r, cols w*16 + kq16*4 + 0..3 -> one float4
  {
    int node = blockIdx.x*8 + (r >> 1);
    int b = r & 1;
    float4 o;
    o.x = fmaxf(acc[0], 0.f); o.y = fmaxf(acc[1], 0.f);
    o.z = fmaxf(acc[2], 0.f); o.w = fmaxf(acc[3], 0.f);
    *(float4*)&out[(size_t)(b*N_NODES + node)*FEAT + w*16 + kq16*4] = o;
  }
}

extern "C" void kernel_launch(void* const* d_in, const int* in_sizes, int n_in,
                              void* d_out, int out_size, void* d_ws, size_t ws_size,
                              hipStream_t stream) {
  const float* h  = (const float*)d_in[0];
  const float* W1 = (const float*)d_in[1];
  const float* W2 = (const float*)d_in[2];
  const float* a  = (const float*)d_in[3];
  const int* src  = (const int*)d_in[4];
  const int* dst  = (const int*)d_in[5];
  float* out = (float*)d_out;

  char* w = (char*)d_ws;
  __bf16* g   = (__bf16*)w;                          w += (size_t)RTOT*FEAT*2;   // 25.6MB interleaved
  float* s_i  = (float*)w;                           w += (size_t)RTOT*4;
  float* s_j  = (float*)w;                           w += (size_t)RTOT*4;
  __bf16* W1t = (__bf16*)w;                          w += FEAT*FEAT*2;
  __bf16* W2t = (__bf16*)w;                          w += FEAT*FEAT*2;
  int* cnt  = (int*)w;                               w += N_NODES*4;
  int* off  = (int*)w;                               w += (N_NODES+1)*4;
  int* curs = (int*)w;                               w += N_NODES*4;
  int* dste = (int*)w;                               w += N_EDGES*4;

  k_prep<<<(N_NODES+255)/256,256,0,stream>>>(W1,W2,W1t,W2t,cnt);

  int gemm_grid = (RTOT + 63)/64;
  k_gemm1_mfma<<<gemm_grid,256,0,stream>>>(h,W1t,a,g,s_i,s_j,src,cnt);

  int nb = (N_NODES+1023)/1024;
  k_scan<<<nb,1024,0,stream>>>(cnt,off,curs);
  k_fill<<<(N_EDGES+255)/256,256,0,stream>>>(src,dst,curs,dste);

  k_agg2<<<N_NODES/8,512,0,stream>>>((const unsigned int*)g,s_i,s_j,off,dste,W2t,out);
}